// Round 16
// baseline (28.638 us; speedup 1.0000x reference)
//
#include <hip/hip_runtime.h>

// QCQP quaternion loss. Per element: smallest eigenpair of 4x4 symmetric A
// via char-poly + monotone Newton from Gershgorin lower bound; eigenvector
// via rank-1 adjugate (adj(A-lam I)*ones ~ v); loss = 8(1-<w,qt>^2/|w|^2).
//
// R15: single kernel + 4B memset node. The reduce kernel (~2-3us node) is
// replaced by bare per-block atomicAdd(out, bsum/B) -- no __threadfence, no
// completion counter (R10's 30us cost was the per-block device fence +
// counter spin, not the add itself). Newton 8->6 (absmax slack is huge;
// monotone-from-below). Pipeline = R12/R13 proven: PAIRS=2 pinned-asm
// loads, vmcnt(7)/vmcnt(0), DPP wave reduce.

#define TPB 256
#define PAIRS 2

typedef float vf4 __attribute__((ext_vector_type(4)));
typedef float vf2 __attribute__((ext_vector_type(2)));

struct Pair { vf4 f0, f1, f2, f3, f4, q0, q1; };

__device__ __forceinline__ void issue_loads(const float* a, const float* q,
                                            Pair& d) {
    unsigned long long aa = (unsigned long long)a;
    unsigned long long qq = (unsigned long long)q;
    asm volatile("global_load_dwordx4 %0, %1, off"           : "=v"(d.f0) : "v"(aa));
    asm volatile("global_load_dwordx4 %0, %1, off offset:16" : "=v"(d.f1) : "v"(aa));
    asm volatile("global_load_dwordx4 %0, %1, off offset:32" : "=v"(d.f2) : "v"(aa));
    asm volatile("global_load_dwordx4 %0, %1, off offset:48" : "=v"(d.f3) : "v"(aa));
    asm volatile("global_load_dwordx4 %0, %1, off offset:64" : "=v"(d.f4) : "v"(aa));
    asm volatile("global_load_dwordx4 %0, %1, off"           : "=v"(d.q0) : "v"(qq));
    asm volatile("global_load_dwordx4 %0, %1, off offset:16" : "=v"(d.q1) : "v"(qq));
}

__device__ __forceinline__ vf2 vmin2(vf2 a, vf2 b){ return __builtin_elementwise_min(a,b); }
__device__ __forceinline__ vf2 vmax2(vf2 a, vf2 b){ return __builtin_elementwise_max(a,b); }
__device__ __forceinline__ vf2 vabs2(vf2 a){ return __builtin_elementwise_abs(a); }
__device__ __forceinline__ vf2 splat2(float s){ vf2 r; r.x = s; r.y = s; return r; }
__device__ __forceinline__ vf2 rcp2(vf2 a){
    vf2 r; r.x = __builtin_amdgcn_rcpf(a.x); r.y = __builtin_amdgcn_rcpf(a.y);
    return r;
}

// ---- pair solve (elem0 = .x, elem1 = .y): returns {loss0, loss1} ----
__device__ __forceinline__ vf2 solve_pair(const vf2 a[10],
                                          vf2 qx, vf2 qy, vf2 qz, vf2 qw) {
    vf2 m00 = -a[0], m01 = -a[1], m02 = -a[2], m03 = -a[3];
    vf2 m11 = -a[4], m12 = -a[5], m13 = -a[6];
    vf2 m22 = -a[7], m23 = -a[8], m33 = -a[9];

    vf2 e1 = m00 + m11 + m22 + m33;
    vf2 e2 = m00*m11 - m01*m01 + m00*m22 - m02*m02 + m00*m33 - m03*m03
           + m11*m22 - m12*m12 + m11*m33 - m13*m13 + m22*m33 - m23*m23;

    vf2 x01 = m02*m13 - m12*m03;
    vf2 x02 = m02*m23 - m22*m03;
    vf2 x03 = m02*m33 - m23*m03;
    vf2 x12 = m12*m23 - m22*m13;
    vf2 x13 = m12*m33 - m23*m13;
    vf2 x23 = m22*m33 - m23*m23;
    vf2 cw0 =  (m11*x23 - m12*x13 + m13*x12);
    vf2 cw1 = -(m01*x23 - m12*x03 + m13*x02);
    vf2 cw2 =  (m01*x13 - m11*x03 + m13*x01);
    vf2 cw3 = -(m01*x12 - m11*x02 + m12*x01);
    vf2 e4 = m00*cw0 + m01*cw1 + m02*cw2 + m03*cw3;

    vf2 e3 = cw0
           + (m00*x23 - m02*x03 + m03*x02)
           + (m00*(m11*m33 - m13*m13) - m01*(m01*m33 - m03*m13)
              + m03*(m01*m13 - m03*m11))
           + (m00*(m11*m22 - m12*m12) - m01*(m01*m22 - m02*m12)
              + m02*(m01*m12 - m02*m11));

    vf2 s0v = vabs2(m01) + vabs2(m02) + vabs2(m03);
    vf2 s1v = vabs2(m01) + vabs2(m12) + vabs2(m13);
    vf2 s2v = vabs2(m02) + vabs2(m12) + vabs2(m23);
    vf2 s3v = vabs2(m03) + vabs2(m13) + vabs2(m23);
    vf2 lo = vmin2(vmin2(m00 - s0v, m11 - s1v), vmin2(m22 - s2v, m33 - s3v))
           - splat2(1e-3f);
    vf2 hi = vmin2(vmin2(m00, m11), vmin2(m22, m33));
    vf2 lam = lo;
    vf2 ndpcap = splat2(-1e-12f);
    #pragma unroll
    for (int it = 0; it < 6; ++it) {
        vf2 p  = (((lam - e1)*lam + e2)*lam - e3)*lam + e4;
        vf2 dp = ((4.f*lam - 3.f*e1)*lam + 2.f*e2)*lam - e3;
        dp = vmin2(dp, ndpcap);
        lam = lam - p * rcp2(dp);
        lam = vmin2(vmax2(lam, lo), hi);
    }

    vf2 r00 = m00 - lam, r11 = m11 - lam, r22 = m22 - lam, r33 = m33 - lam;
    vf2 sm01 = m02*m13 - m12*m03;
    vf2 sm02 = m02*m23 - r22*m03;
    vf2 sm03 = m02*r33 - m23*m03;
    vf2 sm12 = m12*m23 - r22*m13;
    vf2 sm13 = m12*r33 - m23*m13;
    vf2 sm23 = r22*r33 - m23*m23;
    vf2 tm01 = r00*r11 - m01*m01;
    vf2 tm02 = r00*m12 - m02*m01;
    vf2 tm03 = r00*m13 - m03*m01;
    vf2 tm12 = m01*m12 - m02*r11;
    vf2 tm13 = m01*m13 - m03*r11;
    vf2 tm23 = m02*m13 - m03*m12;
    vf2 u0 = m01 - r00, u1 = r11 - m01, u2 = m12 - m02, u3 = m13 - m03;
    vf2 y0 = m03 - m02, y1 = m13 - m12, y2 = m23 - r22, y3 = r33 - m23;
    vf2 w0 =  (u1*sm23 - u2*sm13 + u3*sm12)
            + (y1*tm23 - y2*tm13 + y3*tm12);
    vf2 w1 = -(u0*sm23 - u2*sm03 + u3*sm02)
            - (y0*tm23 - y2*tm03 + y3*tm02);
    vf2 w2 =  (u0*sm13 - u1*sm03 + u3*sm01)
            + (y0*tm13 - y1*tm03 + y3*tm01);
    vf2 w3 = -(u0*sm12 - u1*sm02 + u2*sm01)
            - (y0*tm12 - y1*tm02 + y2*tm01);
    vf2 bn = w0*w0 + w1*w1 + w2*w2 + w3*w3;

    vf2 d = w0*qx + w1*qy + w2*qz + w3*qw;
    vf2 inv = rcp2(vmax2(bn, splat2(1e-20f)));
    vf2 loss = 8.f * (bn - d*d) * inv;
    return vmin2(vmax2(loss, splat2(0.f)), splat2(8.f));
}

__device__ __forceinline__ float solve_elem(const float a[10], float4 qt) {
    vf2 aa[10];
    #pragma unroll
    for (int i = 0; i < 10; ++i) { aa[i].x = a[i]; aa[i].y = a[i]; }
    vf2 L = solve_pair(aa, splat2(qt.x), splat2(qt.y), splat2(qt.z), splat2(qt.w));
    return L.x;
}

// DPP wave64 sum step: VALU pipe only. ctrl/mask are compile-time consts.
template <int CTRL, int ROW_MASK>
__device__ __forceinline__ float dpp_add(float v) {
    int t = __builtin_amdgcn_update_dpp(0, __builtin_bit_cast(int, v),
                                        CTRL, ROW_MASK, 0xf, true);
    return v + __builtin_bit_cast(float, t);
}

__device__ __forceinline__ float wave_sum(float v) {
    v = dpp_add<0x111, 0xf>(v);   // row_shr:1
    v = dpp_add<0x112, 0xf>(v);   // row_shr:2
    v = dpp_add<0x114, 0xf>(v);   // row_shr:4
    v = dpp_add<0x118, 0xf>(v);   // row_shr:8
    v = dpp_add<0x142, 0xa>(v);   // row_bcast:15 -> rows 1,3
    v = dpp_add<0x143, 0xc>(v);   // row_bcast:31 -> rows 2,3
    return __builtin_bit_cast(float,
        __builtin_amdgcn_readlane(__builtin_bit_cast(int, v), 63));
}

__global__ __launch_bounds__(TPB) void qcqp_loss_kernel(
    const float* __restrict__ A_vec, const float* __restrict__ q_t,
    float* __restrict__ out, int B, int T, float invB)
{
    int t = blockIdx.x * blockDim.x + threadIdx.x;
    int Ptot = B >> 1;                       // whole pairs
    float lsum = 0.f;

    Pair Pd, Nd;
    int curp = t;
    {
        int c = (curp < Ptot) ? curp : 0;
        issue_loads(A_vec + (size_t)c * 20, q_t + (size_t)c * 8, Pd);
    }
    int nxtp = curp;

    #define STEP(K, VMSTR)                                                    \
    {                                                                         \
        if ((K) + 1 < PAIRS) {                                                \
            nxtp = t + ((K) + 1) * T;                                         \
            int nc = (nxtp < Ptot) ? nxtp : 0;                                \
            issue_loads(A_vec + (size_t)nc * 20, q_t + (size_t)nc * 8, Nd);   \
        }                                                                     \
        asm volatile("s_waitcnt vmcnt(" VMSTR ")" ::: "memory");              \
        __builtin_amdgcn_sched_barrier(0);                                    \
        {                                                                     \
            bool ok = (curp < Ptot);                                          \
            vf2 aa[10];                                                       \
            aa[0] = (vf2){Pd.f0.x, Pd.f2.z};                                  \
            aa[1] = (vf2){Pd.f0.y, Pd.f2.w};                                  \
            aa[2] = (vf2){Pd.f0.z, Pd.f3.x};                                  \
            aa[3] = (vf2){Pd.f0.w, Pd.f3.y};                                  \
            aa[4] = (vf2){Pd.f1.x, Pd.f3.z};                                  \
            aa[5] = (vf2){Pd.f1.y, Pd.f3.w};                                  \
            aa[6] = (vf2){Pd.f1.z, Pd.f4.x};                                  \
            aa[7] = (vf2){Pd.f1.w, Pd.f4.y};                                  \
            aa[8] = (vf2){Pd.f2.x, Pd.f4.z};                                  \
            aa[9] = (vf2){Pd.f2.y, Pd.f4.w};                                  \
            vf2 qx = (vf2){Pd.q0.x, Pd.q1.x};                                 \
            vf2 qy = (vf2){Pd.q0.y, Pd.q1.y};                                 \
            vf2 qz = (vf2){Pd.q0.z, Pd.q1.z};                                 \
            vf2 qw = (vf2){Pd.q0.w, Pd.q1.w};                                 \
            vf2 L = solve_pair(aa, qx, qy, qz, qw);                           \
            lsum += ok ? (L.x + L.y) : 0.f;                                   \
        }                                                                     \
        Pd = Nd; curp = nxtp;                                                 \
    }

    STEP(0, "7")
    STEP(1, "0")
    #undef STEP

    // odd-B tail element handled once by global thread 0 (dead for even B)
    if ((B & 1) && t == 0) {
        const float* av = A_vec + (size_t)(B - 1) * 10;
        float2 v01 = *(const float2*)(av + 0);
        float2 v23 = *(const float2*)(av + 2);
        float2 v45 = *(const float2*)(av + 4);
        float2 v67 = *(const float2*)(av + 6);
        float2 v89 = *(const float2*)(av + 8);
        float a0[10] = {v01.x, v01.y, v23.x, v23.y, v45.x,
                        v45.y, v67.x, v67.y, v89.x, v89.y};
        float4 qt0 = *(const float4*)(q_t + (size_t)(B - 1) * 4);
        lsum += solve_elem(a0, qt0);
    }

    float wsum = wave_sum(lsum);

    __shared__ float sm[TPB / 64];
    int lane = threadIdx.x & 63, wid = threadIdx.x >> 6;
    if (lane == 0) sm[wid] = wsum;
    __syncthreads();
    if (threadIdx.x == 0) {
        float bsum = sm[0] + sm[1] + sm[2] + sm[3];
        atomicAdd(out, bsum * invB);   // bare atomic: no fence, no counter
    }
}

extern "C" void kernel_launch(void* const* d_in, const int* in_sizes, int n_in,
                              void* d_out, int out_size, void* d_ws, size_t ws_size,
                              hipStream_t stream)
{
    const float* A_vec = (const float*)d_in[0];
    const float* q_t   = (const float*)d_in[1];
    int B = in_sizes[0] / 10;

    (void)hipMemsetAsync(d_out, 0, sizeof(float), stream);
    int Ptot = B >> 1;
    int nblocks = (Ptot + TPB * PAIRS - 1) / (TPB * PAIRS);
    int T = nblocks * TPB;                  // thread count; pair idx = t + k*T
    qcqp_loss_kernel<<<nblocks, TPB, 0, stream>>>(
        A_vec, q_t, (float*)d_out, B, T, 1.0f / (float)B);
}

// Round 17
// 17.431 us; speedup vs baseline: 1.6429x; 1.6429x over previous
//
#include <hip/hip_runtime.h>

// QCQP quaternion loss. Per element: smallest eigenpair of 4x4 symmetric A
// via char-poly + monotone Newton from Gershgorin lower bound; eigenvector
// via rank-1 adjugate (adj(A-lam I)*ones ~ v); loss = 8(1-<w,qt>^2/|w|^2).
//
// R16 = R13's proven two-kernel structure (18.55us) + two validated trims:
//   (a) Newton 8->6 (R15 passed absmax 0 with 6; monotone-from-below),
//   (b) reduce kernel reads partials as float4 (one dwordx4/lane).
// LEDGER: atomics on hot path are poison here (R10: +30us fence+counter,
// R15: +10us bare add @1024 blocks). Plain-store partials + tiny reduce
// kernel is the right endgame shape. pk-fp32 (R13) and 8 waves/SIMD (R14)
// are nulls: main kernel is VALU-instruction-bound.

#define TPB 256
#define PAIRS 2

typedef float vf4 __attribute__((ext_vector_type(4)));
typedef float vf2 __attribute__((ext_vector_type(2)));

struct Pair { vf4 f0, f1, f2, f3, f4, q0, q1; };

__device__ __forceinline__ void issue_loads(const float* a, const float* q,
                                            Pair& d) {
    unsigned long long aa = (unsigned long long)a;
    unsigned long long qq = (unsigned long long)q;
    asm volatile("global_load_dwordx4 %0, %1, off"           : "=v"(d.f0) : "v"(aa));
    asm volatile("global_load_dwordx4 %0, %1, off offset:16" : "=v"(d.f1) : "v"(aa));
    asm volatile("global_load_dwordx4 %0, %1, off offset:32" : "=v"(d.f2) : "v"(aa));
    asm volatile("global_load_dwordx4 %0, %1, off offset:48" : "=v"(d.f3) : "v"(aa));
    asm volatile("global_load_dwordx4 %0, %1, off offset:64" : "=v"(d.f4) : "v"(aa));
    asm volatile("global_load_dwordx4 %0, %1, off"           : "=v"(d.q0) : "v"(qq));
    asm volatile("global_load_dwordx4 %0, %1, off offset:16" : "=v"(d.q1) : "v"(qq));
}

__device__ __forceinline__ vf2 vmin2(vf2 a, vf2 b){ return __builtin_elementwise_min(a,b); }
__device__ __forceinline__ vf2 vmax2(vf2 a, vf2 b){ return __builtin_elementwise_max(a,b); }
__device__ __forceinline__ vf2 vabs2(vf2 a){ return __builtin_elementwise_abs(a); }
__device__ __forceinline__ vf2 splat2(float s){ vf2 r; r.x = s; r.y = s; return r; }
__device__ __forceinline__ vf2 rcp2(vf2 a){
    vf2 r; r.x = __builtin_amdgcn_rcpf(a.x); r.y = __builtin_amdgcn_rcpf(a.y);
    return r;
}

// ---- pair solve (elem0 = .x, elem1 = .y): returns {loss0, loss1} ----
__device__ __forceinline__ vf2 solve_pair(const vf2 a[10],
                                          vf2 qx, vf2 qy, vf2 qz, vf2 qw) {
    vf2 m00 = -a[0], m01 = -a[1], m02 = -a[2], m03 = -a[3];
    vf2 m11 = -a[4], m12 = -a[5], m13 = -a[6];
    vf2 m22 = -a[7], m23 = -a[8], m33 = -a[9];

    vf2 e1 = m00 + m11 + m22 + m33;
    vf2 e2 = m00*m11 - m01*m01 + m00*m22 - m02*m02 + m00*m33 - m03*m03
           + m11*m22 - m12*m12 + m11*m33 - m13*m13 + m22*m33 - m23*m23;

    vf2 x01 = m02*m13 - m12*m03;
    vf2 x02 = m02*m23 - m22*m03;
    vf2 x03 = m02*m33 - m23*m03;
    vf2 x12 = m12*m23 - m22*m13;
    vf2 x13 = m12*m33 - m23*m13;
    vf2 x23 = m22*m33 - m23*m23;
    vf2 cw0 =  (m11*x23 - m12*x13 + m13*x12);
    vf2 cw1 = -(m01*x23 - m12*x03 + m13*x02);
    vf2 cw2 =  (m01*x13 - m11*x03 + m13*x01);
    vf2 cw3 = -(m01*x12 - m11*x02 + m12*x01);
    vf2 e4 = m00*cw0 + m01*cw1 + m02*cw2 + m03*cw3;

    vf2 e3 = cw0
           + (m00*x23 - m02*x03 + m03*x02)
           + (m00*(m11*m33 - m13*m13) - m01*(m01*m33 - m03*m13)
              + m03*(m01*m13 - m03*m11))
           + (m00*(m11*m22 - m12*m12) - m01*(m01*m22 - m02*m12)
              + m02*(m01*m12 - m02*m11));

    vf2 s0v = vabs2(m01) + vabs2(m02) + vabs2(m03);
    vf2 s1v = vabs2(m01) + vabs2(m12) + vabs2(m13);
    vf2 s2v = vabs2(m02) + vabs2(m12) + vabs2(m23);
    vf2 s3v = vabs2(m03) + vabs2(m13) + vabs2(m23);
    vf2 lo = vmin2(vmin2(m00 - s0v, m11 - s1v), vmin2(m22 - s2v, m33 - s3v))
           - splat2(1e-3f);
    vf2 hi = vmin2(vmin2(m00, m11), vmin2(m22, m33));
    vf2 lam = lo;
    vf2 ndpcap = splat2(-1e-12f);
    #pragma unroll
    for (int it = 0; it < 6; ++it) {
        vf2 p  = (((lam - e1)*lam + e2)*lam - e3)*lam + e4;
        vf2 dp = ((4.f*lam - 3.f*e1)*lam + 2.f*e2)*lam - e3;
        dp = vmin2(dp, ndpcap);
        lam = lam - p * rcp2(dp);
        lam = vmin2(vmax2(lam, lo), hi);
    }

    vf2 r00 = m00 - lam, r11 = m11 - lam, r22 = m22 - lam, r33 = m33 - lam;
    vf2 sm01 = m02*m13 - m12*m03;
    vf2 sm02 = m02*m23 - r22*m03;
    vf2 sm03 = m02*r33 - m23*m03;
    vf2 sm12 = m12*m23 - r22*m13;
    vf2 sm13 = m12*r33 - m23*m13;
    vf2 sm23 = r22*r33 - m23*m23;
    vf2 tm01 = r00*r11 - m01*m01;
    vf2 tm02 = r00*m12 - m02*m01;
    vf2 tm03 = r00*m13 - m03*m01;
    vf2 tm12 = m01*m12 - m02*r11;
    vf2 tm13 = m01*m13 - m03*r11;
    vf2 tm23 = m02*m13 - m03*m12;
    vf2 u0 = m01 - r00, u1 = r11 - m01, u2 = m12 - m02, u3 = m13 - m03;
    vf2 y0 = m03 - m02, y1 = m13 - m12, y2 = m23 - r22, y3 = r33 - m23;
    vf2 w0 =  (u1*sm23 - u2*sm13 + u3*sm12)
            + (y1*tm23 - y2*tm13 + y3*tm12);
    vf2 w1 = -(u0*sm23 - u2*sm03 + u3*sm02)
            - (y0*tm23 - y2*tm03 + y3*tm02);
    vf2 w2 =  (u0*sm13 - u1*sm03 + u3*sm01)
            + (y0*tm13 - y1*tm03 + y3*tm01);
    vf2 w3 = -(u0*sm12 - u1*sm02 + u2*sm01)
            - (y0*tm12 - y1*tm02 + y2*tm01);
    vf2 bn = w0*w0 + w1*w1 + w2*w2 + w3*w3;

    vf2 d = w0*qx + w1*qy + w2*qz + w3*qw;
    vf2 inv = rcp2(vmax2(bn, splat2(1e-20f)));
    vf2 loss = 8.f * (bn - d*d) * inv;
    return vmin2(vmax2(loss, splat2(0.f)), splat2(8.f));
}

__device__ __forceinline__ float solve_elem(const float a[10], float4 qt) {
    vf2 aa[10];
    #pragma unroll
    for (int i = 0; i < 10; ++i) { aa[i].x = a[i]; aa[i].y = a[i]; }
    vf2 L = solve_pair(aa, splat2(qt.x), splat2(qt.y), splat2(qt.z), splat2(qt.w));
    return L.x;
}

// DPP wave64 sum step: VALU pipe only. ctrl/mask are compile-time consts.
template <int CTRL, int ROW_MASK>
__device__ __forceinline__ float dpp_add(float v) {
    int t = __builtin_amdgcn_update_dpp(0, __builtin_bit_cast(int, v),
                                        CTRL, ROW_MASK, 0xf, true);
    return v + __builtin_bit_cast(float, t);
}

__device__ __forceinline__ float wave_sum(float v) {
    v = dpp_add<0x111, 0xf>(v);   // row_shr:1
    v = dpp_add<0x112, 0xf>(v);   // row_shr:2
    v = dpp_add<0x114, 0xf>(v);   // row_shr:4
    v = dpp_add<0x118, 0xf>(v);   // row_shr:8
    v = dpp_add<0x142, 0xa>(v);   // row_bcast:15 -> rows 1,3
    v = dpp_add<0x143, 0xc>(v);   // row_bcast:31 -> rows 2,3
    return __builtin_bit_cast(float,
        __builtin_amdgcn_readlane(__builtin_bit_cast(int, v), 63));
}

__global__ __launch_bounds__(TPB) void qcqp_loss_kernel(
    const float* __restrict__ A_vec, const float* __restrict__ q_t,
    float* __restrict__ part, int B, int T)
{
    int t = blockIdx.x * blockDim.x + threadIdx.x;
    int Ptot = B >> 1;                       // whole pairs
    float lsum = 0.f;

    Pair Pd, Nd;
    int curp = t;
    {
        int c = (curp < Ptot) ? curp : 0;
        issue_loads(A_vec + (size_t)c * 20, q_t + (size_t)c * 8, Pd);
    }
    int nxtp = curp;

    #define STEP(K, VMSTR)                                                    \
    {                                                                         \
        if ((K) + 1 < PAIRS) {                                                \
            nxtp = t + ((K) + 1) * T;                                         \
            int nc = (nxtp < Ptot) ? nxtp : 0;                                \
            issue_loads(A_vec + (size_t)nc * 20, q_t + (size_t)nc * 8, Nd);   \
        }                                                                     \
        asm volatile("s_waitcnt vmcnt(" VMSTR ")" ::: "memory");              \
        __builtin_amdgcn_sched_barrier(0);                                    \
        {                                                                     \
            bool ok = (curp < Ptot);                                          \
            vf2 aa[10];                                                       \
            aa[0] = (vf2){Pd.f0.x, Pd.f2.z};                                  \
            aa[1] = (vf2){Pd.f0.y, Pd.f2.w};                                  \
            aa[2] = (vf2){Pd.f0.z, Pd.f3.x};                                  \
            aa[3] = (vf2){Pd.f0.w, Pd.f3.y};                                  \
            aa[4] = (vf2){Pd.f1.x, Pd.f3.z};                                  \
            aa[5] = (vf2){Pd.f1.y, Pd.f3.w};                                  \
            aa[6] = (vf2){Pd.f1.z, Pd.f4.x};                                  \
            aa[7] = (vf2){Pd.f1.w, Pd.f4.y};                                  \
            aa[8] = (vf2){Pd.f2.x, Pd.f4.z};                                  \
            aa[9] = (vf2){Pd.f2.y, Pd.f4.w};                                  \
            vf2 qx = (vf2){Pd.q0.x, Pd.q1.x};                                 \
            vf2 qy = (vf2){Pd.q0.y, Pd.q1.y};                                 \
            vf2 qz = (vf2){Pd.q0.z, Pd.q1.z};                                 \
            vf2 qw = (vf2){Pd.q0.w, Pd.q1.w};                                 \
            vf2 L = solve_pair(aa, qx, qy, qz, qw);                           \
            lsum += ok ? (L.x + L.y) : 0.f;                                   \
        }                                                                     \
        Pd = Nd; curp = nxtp;                                                 \
    }

    STEP(0, "7")
    STEP(1, "0")
    #undef STEP

    float wsum = wave_sum(lsum);

    __shared__ float sm[TPB / 64];
    int lane = threadIdx.x & 63, wid = threadIdx.x >> 6;
    if (lane == 0) sm[wid] = wsum;
    __syncthreads();
    if (threadIdx.x == 0)
        part[blockIdx.x] = sm[0] + sm[1] + sm[2] + sm[3];   // plain store
}

__global__ __launch_bounds__(TPB) void qcqp_reduce_kernel(
    const float* __restrict__ part, const float* __restrict__ A_vec,
    const float* __restrict__ q_t, float* __restrict__ out,
    int nparts, int B)
{
    // nparts is a multiple of 4 here (1024); read as float4, grid-stride.
    float s = 0.f;
    int nvec = nparts >> 2;
    const float4* p4 = (const float4*)part;
    for (int i = threadIdx.x; i < nvec; i += TPB) {
        float4 v = p4[i];
        s += (v.x + v.y) + (v.z + v.w);
    }
    int rem = nparts & 3;             // tail partials (if nparts % 4 != 0)
    if (threadIdx.x < rem)
        s += part[nparts - 1 - threadIdx.x];
    float wsum = wave_sum(s);

    __shared__ float sm[TPB / 64];
    int lane = threadIdx.x & 63, wid = threadIdx.x >> 6;
    if (lane == 0) sm[wid] = wsum;
    __syncthreads();
    if (threadIdx.x == 0) {
        float total = sm[0] + sm[1] + sm[2] + sm[3];
        if (B & 1) {   // odd-B tail element (not hit for B=2^20)
            const float* av = A_vec + (size_t)(B - 1) * 10;
            float2 v01 = *(const float2*)(av + 0);
            float2 v23 = *(const float2*)(av + 2);
            float2 v45 = *(const float2*)(av + 4);
            float2 v67 = *(const float2*)(av + 6);
            float2 v89 = *(const float2*)(av + 8);
            float a0[10] = {v01.x, v01.y, v23.x, v23.y, v45.x,
                            v45.y, v67.x, v67.y, v89.x, v89.y};
            float4 qt0 = *(const float4*)(q_t + (size_t)(B - 1) * 4);
            total += solve_elem(a0, qt0);
        }
        out[0] = total / (float)B;
    }
}

extern "C" void kernel_launch(void* const* d_in, const int* in_sizes, int n_in,
                              void* d_out, int out_size, void* d_ws, size_t ws_size,
                              hipStream_t stream)
{
    const float* A_vec = (const float*)d_in[0];
    const float* q_t   = (const float*)d_in[1];
    int B = in_sizes[0] / 10;
    float* part = (float*)d_ws;

    int Ptot = B >> 1;
    int nblocks = (Ptot + TPB * PAIRS - 1) / (TPB * PAIRS);
    int T = nblocks * TPB;                  // thread count; pair idx = t + k*T
    qcqp_loss_kernel<<<nblocks, TPB, 0, stream>>>(A_vec, q_t, part, B, T);
    qcqp_reduce_kernel<<<1, TPB, 0, stream>>>(part, A_vec, q_t,
                                              (float*)d_out, nblocks, B);
}

// Round 18
// 17.122 us; speedup vs baseline: 1.6726x; 1.0181x over previous
//
#include <hip/hip_runtime.h>

// QCQP quaternion loss. Per element: smallest eigenpair of 4x4 symmetric A
// via char-poly + monotone Newton from Gershgorin lower bound; eigenvector
// = generalized cross of rows 1,2,3 of M = A-lam*I (prop. to null vector v
// unless v0==0 exactly, prob ~1e-6, loss clamped -> mean shift <=8e-6);
// loss = 8(1-<w,qt>^2/|w|^2). Mean-reduce via plain-store partials.
//
// R17 = R16 (17.43us) + two VALU cuts:
//   (a) single-cross eigenvector (6 minors + 1 comb, was 12 + 2),
//   (b) Newton clamps moved out of the loop (convexity below smallest root
//       => monotone no-overshoot; dp-cap per iter + one final clamp).
// LEDGER: atomics on hot path poison (R10 +30us, R15 +10us); pk-fp32 null
// (R13); 8 waves/SIMD null (R14). Two-kernel plain-store shape is final.

#define TPB 256
#define PAIRS 2

typedef float vf4 __attribute__((ext_vector_type(4)));
typedef float vf2 __attribute__((ext_vector_type(2)));

struct Pair { vf4 f0, f1, f2, f3, f4, q0, q1; };

__device__ __forceinline__ void issue_loads(const float* a, const float* q,
                                            Pair& d) {
    unsigned long long aa = (unsigned long long)a;
    unsigned long long qq = (unsigned long long)q;
    asm volatile("global_load_dwordx4 %0, %1, off"           : "=v"(d.f0) : "v"(aa));
    asm volatile("global_load_dwordx4 %0, %1, off offset:16" : "=v"(d.f1) : "v"(aa));
    asm volatile("global_load_dwordx4 %0, %1, off offset:32" : "=v"(d.f2) : "v"(aa));
    asm volatile("global_load_dwordx4 %0, %1, off offset:48" : "=v"(d.f3) : "v"(aa));
    asm volatile("global_load_dwordx4 %0, %1, off offset:64" : "=v"(d.f4) : "v"(aa));
    asm volatile("global_load_dwordx4 %0, %1, off"           : "=v"(d.q0) : "v"(qq));
    asm volatile("global_load_dwordx4 %0, %1, off offset:16" : "=v"(d.q1) : "v"(qq));
}

__device__ __forceinline__ vf2 vmin2(vf2 a, vf2 b){ return __builtin_elementwise_min(a,b); }
__device__ __forceinline__ vf2 vmax2(vf2 a, vf2 b){ return __builtin_elementwise_max(a,b); }
__device__ __forceinline__ vf2 vabs2(vf2 a){ return __builtin_elementwise_abs(a); }
__device__ __forceinline__ vf2 splat2(float s){ vf2 r; r.x = s; r.y = s; return r; }
__device__ __forceinline__ vf2 rcp2(vf2 a){
    vf2 r; r.x = __builtin_amdgcn_rcpf(a.x); r.y = __builtin_amdgcn_rcpf(a.y);
    return r;
}

// ---- pair solve (elem0 = .x, elem1 = .y): returns {loss0, loss1} ----
__device__ __forceinline__ vf2 solve_pair(const vf2 a[10],
                                          vf2 qx, vf2 qy, vf2 qz, vf2 qw) {
    vf2 m00 = -a[0], m01 = -a[1], m02 = -a[2], m03 = -a[3];
    vf2 m11 = -a[4], m12 = -a[5], m13 = -a[6];
    vf2 m22 = -a[7], m23 = -a[8], m33 = -a[9];

    vf2 e1 = m00 + m11 + m22 + m33;
    vf2 e2 = m00*m11 - m01*m01 + m00*m22 - m02*m02 + m00*m33 - m03*m03
           + m11*m22 - m12*m12 + m11*m33 - m13*m13 + m22*m33 - m23*m23;

    vf2 x01 = m02*m13 - m12*m03;
    vf2 x02 = m02*m23 - m22*m03;
    vf2 x03 = m02*m33 - m23*m03;
    vf2 x12 = m12*m23 - m22*m13;
    vf2 x13 = m12*m33 - m23*m13;
    vf2 x23 = m22*m33 - m23*m23;
    vf2 cw0 =  (m11*x23 - m12*x13 + m13*x12);
    vf2 cw1 = -(m01*x23 - m12*x03 + m13*x02);
    vf2 cw2 =  (m01*x13 - m11*x03 + m13*x01);
    vf2 cw3 = -(m01*x12 - m11*x02 + m12*x01);
    vf2 e4 = m00*cw0 + m01*cw1 + m02*cw2 + m03*cw3;

    vf2 e3 = cw0
           + (m00*x23 - m02*x03 + m03*x02)
           + (m00*(m11*m33 - m13*m13) - m01*(m01*m33 - m03*m13)
              + m03*(m01*m13 - m03*m11))
           + (m00*(m11*m22 - m12*m12) - m01*(m01*m22 - m02*m12)
              + m02*(m01*m12 - m02*m11));

    vf2 s0v = vabs2(m01) + vabs2(m02) + vabs2(m03);
    vf2 s1v = vabs2(m01) + vabs2(m12) + vabs2(m13);
    vf2 s2v = vabs2(m02) + vabs2(m12) + vabs2(m23);
    vf2 s3v = vabs2(m03) + vabs2(m13) + vabs2(m23);
    vf2 lo = vmin2(vmin2(m00 - s0v, m11 - s1v), vmin2(m22 - s2v, m33 - s3v))
           - splat2(1e-3f);
    vf2 hi = vmin2(vmin2(m00, m11), vmin2(m22, m33));
    vf2 lam = lo;
    vf2 ndpcap = splat2(-1e-12f);
    // Monotone Newton from below: p>0, p'<0, p''>0 on (-inf, lam_min), so
    // exact iterates never overshoot; dp-cap guards rounding, clamp once.
    #pragma unroll
    for (int it = 0; it < 6; ++it) {
        vf2 p  = (((lam - e1)*lam + e2)*lam - e3)*lam + e4;
        vf2 dp = ((4.f*lam - 3.f*e1)*lam + 2.f*e2)*lam - e3;
        dp = vmin2(dp, ndpcap);
        lam = lam - p * rcp2(dp);
    }
    lam = vmin2(vmax2(lam, lo), hi);

    // eigenvector = cross of rows 1,2,3 of M = A - lam I
    // R1 = {m01, r11, m12, m13}, R2 = {m02, m12, r22, m23},
    // R3 = {m03, m13, m23, r33}
    vf2 r11 = m11 - lam, r22 = m22 - lam, r33 = m33 - lam;
    vf2 s01 = m02*m13 - m12*m03;
    vf2 s02 = m02*m23 - r22*m03;
    vf2 s03 = m02*r33 - m23*m03;
    vf2 s12 = m12*m23 - r22*m13;
    vf2 s13 = m12*r33 - m23*m13;
    vf2 s23 = r22*r33 - m23*m23;
    vf2 w0 =  (r11*s23 - m12*s13 + m13*s12);
    vf2 w1 = -(m01*s23 - m12*s03 + m13*s02);
    vf2 w2 =  (m01*s13 - r11*s03 + m13*s01);
    vf2 w3 = -(m01*s12 - r11*s02 + m12*s01);
    vf2 bn = w0*w0 + w1*w1 + w2*w2 + w3*w3;

    vf2 d = w0*qx + w1*qy + w2*qz + w3*qw;
    vf2 inv = rcp2(vmax2(bn, splat2(1e-20f)));
    vf2 loss = 8.f * (bn - d*d) * inv;
    return vmin2(vmax2(loss, splat2(0.f)), splat2(8.f));
}

__device__ __forceinline__ float solve_elem(const float a[10], float4 qt) {
    vf2 aa[10];
    #pragma unroll
    for (int i = 0; i < 10; ++i) { aa[i].x = a[i]; aa[i].y = a[i]; }
    vf2 L = solve_pair(aa, splat2(qt.x), splat2(qt.y), splat2(qt.z), splat2(qt.w));
    return L.x;
}

// DPP wave64 sum step: VALU pipe only. ctrl/mask are compile-time consts.
template <int CTRL, int ROW_MASK>
__device__ __forceinline__ float dpp_add(float v) {
    int t = __builtin_amdgcn_update_dpp(0, __builtin_bit_cast(int, v),
                                        CTRL, ROW_MASK, 0xf, true);
    return v + __builtin_bit_cast(float, t);
}

__device__ __forceinline__ float wave_sum(float v) {
    v = dpp_add<0x111, 0xf>(v);   // row_shr:1
    v = dpp_add<0x112, 0xf>(v);   // row_shr:2
    v = dpp_add<0x114, 0xf>(v);   // row_shr:4
    v = dpp_add<0x118, 0xf>(v);   // row_shr:8
    v = dpp_add<0x142, 0xa>(v);   // row_bcast:15 -> rows 1,3
    v = dpp_add<0x143, 0xc>(v);   // row_bcast:31 -> rows 2,3
    return __builtin_bit_cast(float,
        __builtin_amdgcn_readlane(__builtin_bit_cast(int, v), 63));
}

__global__ __launch_bounds__(TPB) void qcqp_loss_kernel(
    const float* __restrict__ A_vec, const float* __restrict__ q_t,
    float* __restrict__ part, int B, int T)
{
    int t = blockIdx.x * blockDim.x + threadIdx.x;
    int Ptot = B >> 1;                       // whole pairs
    float lsum = 0.f;

    Pair Pd, Nd;
    int curp = t;
    {
        int c = (curp < Ptot) ? curp : 0;
        issue_loads(A_vec + (size_t)c * 20, q_t + (size_t)c * 8, Pd);
    }
    int nxtp = curp;

    #define STEP(K, VMSTR)                                                    \
    {                                                                         \
        if ((K) + 1 < PAIRS) {                                                \
            nxtp = t + ((K) + 1) * T;                                         \
            int nc = (nxtp < Ptot) ? nxtp : 0;                                \
            issue_loads(A_vec + (size_t)nc * 20, q_t + (size_t)nc * 8, Nd);   \
        }                                                                     \
        asm volatile("s_waitcnt vmcnt(" VMSTR ")" ::: "memory");              \
        __builtin_amdgcn_sched_barrier(0);                                    \
        {                                                                     \
            bool ok = (curp < Ptot);                                          \
            vf2 aa[10];                                                       \
            aa[0] = (vf2){Pd.f0.x, Pd.f2.z};                                  \
            aa[1] = (vf2){Pd.f0.y, Pd.f2.w};                                  \
            aa[2] = (vf2){Pd.f0.z, Pd.f3.x};                                  \
            aa[3] = (vf2){Pd.f0.w, Pd.f3.y};                                  \
            aa[4] = (vf2){Pd.f1.x, Pd.f3.z};                                  \
            aa[5] = (vf2){Pd.f1.y, Pd.f3.w};                                  \
            aa[6] = (vf2){Pd.f1.z, Pd.f4.x};                                  \
            aa[7] = (vf2){Pd.f1.w, Pd.f4.y};                                  \
            aa[8] = (vf2){Pd.f2.x, Pd.f4.z};                                  \
            aa[9] = (vf2){Pd.f2.y, Pd.f4.w};                                  \
            vf2 qx = (vf2){Pd.q0.x, Pd.q1.x};                                 \
            vf2 qy = (vf2){Pd.q0.y, Pd.q1.y};                                 \
            vf2 qz = (vf2){Pd.q0.z, Pd.q1.z};                                 \
            vf2 qw = (vf2){Pd.q0.w, Pd.q1.w};                                 \
            vf2 L = solve_pair(aa, qx, qy, qz, qw);                           \
            lsum += ok ? (L.x + L.y) : 0.f;                                   \
        }                                                                     \
        Pd = Nd; curp = nxtp;                                                 \
    }

    STEP(0, "7")
    STEP(1, "0")
    #undef STEP

    float wsum = wave_sum(lsum);

    __shared__ float sm[TPB / 64];
    int lane = threadIdx.x & 63, wid = threadIdx.x >> 6;
    if (lane == 0) sm[wid] = wsum;
    __syncthreads();
    if (threadIdx.x == 0)
        part[blockIdx.x] = sm[0] + sm[1] + sm[2] + sm[3];   // plain store
}

__global__ __launch_bounds__(TPB) void qcqp_reduce_kernel(
    const float* __restrict__ part, const float* __restrict__ A_vec,
    const float* __restrict__ q_t, float* __restrict__ out,
    int nparts, int B)
{
    float s = 0.f;
    int nvec = nparts >> 2;
    const float4* p4 = (const float4*)part;
    for (int i = threadIdx.x; i < nvec; i += TPB) {
        float4 v = p4[i];
        s += (v.x + v.y) + (v.z + v.w);
    }
    int rem = nparts & 3;
    if (threadIdx.x < rem)
        s += part[nparts - 1 - threadIdx.x];
    float wsum = wave_sum(s);

    __shared__ float sm[TPB / 64];
    int lane = threadIdx.x & 63, wid = threadIdx.x >> 6;
    if (lane == 0) sm[wid] = wsum;
    __syncthreads();
    if (threadIdx.x == 0) {
        float total = sm[0] + sm[1] + sm[2] + sm[3];
        if (B & 1) {   // odd-B tail element (not hit for B=2^20)
            const float* av = A_vec + (size_t)(B - 1) * 10;
            float2 v01 = *(const float2*)(av + 0);
            float2 v23 = *(const float2*)(av + 2);
            float2 v45 = *(const float2*)(av + 4);
            float2 v67 = *(const float2*)(av + 6);
            float2 v89 = *(const float2*)(av + 8);
            float a0[10] = {v01.x, v01.y, v23.x, v23.y, v45.x,
                            v45.y, v67.x, v67.y, v89.x, v89.y};
            float4 qt0 = *(const float4*)(q_t + (size_t)(B - 1) * 4);
            total += solve_elem(a0, qt0);
        }
        out[0] = total / (float)B;
    }
}

extern "C" void kernel_launch(void* const* d_in, const int* in_sizes, int n_in,
                              void* d_out, int out_size, void* d_ws, size_t ws_size,
                              hipStream_t stream)
{
    const float* A_vec = (const float*)d_in[0];
    const float* q_t   = (const float*)d_in[1];
    int B = in_sizes[0] / 10;
    float* part = (float*)d_ws;

    int Ptot = B >> 1;
    int nblocks = (Ptot + TPB * PAIRS - 1) / (TPB * PAIRS);
    int T = nblocks * TPB;                  // thread count; pair idx = t + k*T
    qcqp_loss_kernel<<<nblocks, TPB, 0, stream>>>(A_vec, q_t, part, B, T);
    qcqp_reduce_kernel<<<1, TPB, 0, stream>>>(part, A_vec, q_t,
                                              (float*)d_out, nblocks, B);
}